// Round 8
// baseline (247.837 us; speedup 1.0000x reference)
//
#include <hip/hip_runtime.h>

typedef unsigned char u8;
typedef float f32x4 __attribute__((ext_vector_type(4)));
typedef float f32x16 __attribute__((ext_vector_type(16)));
typedef int i32x8 __attribute__((ext_vector_type(8)));

#define LL 4096
#define PSTR 144              // P row stride (bytes): 16-B aligned 32-B spans; writes 2-way/free
#define SCALE 16.0f           // x pre-scale before fp8
#define GSCALE (1.0f/256.0f)  // undo SCALE^2 on the gram
#define FREQC (-0.03597789207803197f)   // -ln(10000)/256
#define ONE_SC 0x7F7F7F7F     // E8M0 scale bytes = 127 -> 2^0 = 1.0

__device__ __forceinline__ i32x8 PK16(uint4 a, uint4 b) {
  i32x8 r;
  r[0] = (int)a.x; r[1] = (int)a.y; r[2] = (int)a.z; r[3] = (int)a.w;
  r[4] = (int)b.x; r[5] = (int)b.y; r[6] = (int)b.z; r[7] = (int)b.w;
  return r;
}

typedef __attribute__((address_space(3))) u8 lds_u8;
typedef __attribute__((address_space(1))) u8 glb_u8;
__device__ __forceinline__ void dma16(const u8* g, u8* l) {
  __builtin_amdgcn_global_load_lds((const glb_u8*)g, (lds_u8*)l, 16, 0, 0);
}

// ---------------- prep3 (validated R5): fp8 convert + 16-B-granule swizzled layouts ----------------
//   xbf: row r (256 B): 16-B chunk c stored at ((c ^ (r&15))*16).
//   xT : d-row (4096 B) = 32 j-segments of 128 B; 16-B chunk c (j 16c..16c+15) at ((c ^ (d&7))*16).
__global__ __launch_bounds__(512) void prep3(const float* __restrict__ x, u8* __restrict__ xbf,
                                             u8* __restrict__ xT, float* __restrict__ sq) {
  __shared__ u8 T2[256 * 80];       // col-major fp8: T2[d*80 + local_row], 16-B pad per column
  const int blk = blockIdx.x;
  const int b = blk >> 6, ch = blk & 63;
  const int j0 = ch << 6;           // first of this block's 64 rows
  const int tid = threadIdx.x;
  const int wv = tid >> 6, ln = tid & 63;
  const long bL = (long)b * LL;
  const float4* x4 = (const float4*)x + (bL + j0) * 64;
  unsigned* xb4 = (unsigned*)xbf + (bL + j0) * 64;

  #pragma unroll
  for (int g = 0; g < 2; ++g) {
    int pkw[4];
    #pragma unroll
    for (int ii = 0; ii < 4; ++ii) {
      const int row = 8 * wv + 4 * g + ii;                 // 0..63, wave owns 8 consecutive rows
      float4 v = x4[row * 64 + ln];                        // 1 KB contiguous per wave
      float s = v.x * v.x + v.y * v.y + v.z * v.z + v.w * v.w;
      #pragma unroll
      for (int o = 32; o; o >>= 1) s += __shfl_xor(s, o);
      if (ln == 0) sq[bL + j0 + row] = s;
      int pk = __builtin_amdgcn_cvt_pk_fp8_f32(v.x * SCALE, v.y * SCALE, 0, false);
      pk = __builtin_amdgcn_cvt_pk_fp8_f32(v.z * SCALE, v.w * SCALE, pk, true);
      // 16-B granule swizzle: dword ln belongs to chunk16 (ln>>2); position = chunk ^ (row&15)
      const int sdw = ((((ln >> 2) ^ ((j0 + row) & 15)) << 2)) | (ln & 3);
      xb4[row * 64 + sdw] = (unsigned)pk;                  // 256-B coalesced per wave
      pkw[ii] = pk;
    }
    // 4x4 byte transpose in registers (v_perm_b32), then dword writes into col-major T2.
    const int rb = 8 * wv + 4 * g;                         // first of 4 consecutive rows
    #pragma unroll
    for (int k = 0; k < 4; ++k) {
      const unsigned sel = (unsigned)(k | ((4 + k) << 8));
      unsigned m01 = __builtin_amdgcn_perm((unsigned)pkw[1], (unsigned)pkw[0], sel);
      unsigned m23 = __builtin_amdgcn_perm((unsigned)pkw[3], (unsigned)pkw[2], sel);
      unsigned tw  = __builtin_amdgcn_perm(m23, m01, 0x05040100u);
      *(unsigned*)(T2 + (4 * ln + k) * 80 + rb) = tw;      // rows rb..rb+3 at dim 4*ln+k
    }
  }
  __syncthreads();
  // Phase 2: per d-row, emit this block's 4 16-B chunks (one 64-B contiguous burst per d).
  #pragma unroll
  for (int db = 0; db < 2; ++db) {
    const int d = db * 128 + (tid >> 2);
    const int cl = tid & 3;                                // local chunk16 (16 local rows)
    const int c16 = ((ch & 1) << 2) | cl;                  // global chunk16 within segment
    const int p = c16 ^ (d & 7);                           // swizzled position
    uint4 ov = *(const uint4*)(T2 + d * 80 + 16 * cl);     // 16 consecutive local rows at dim d
    *(uint4*)(xT + (((long)(b << 8) + d) << 12) + ((ch >> 1) << 7) + (p << 4)) = ov;
  }
}

// ---------------- main kernel: WAVE-SPECIALIZED producer/consumer + MX MFMA ----------------
// 256 blocks x 1024 thr (1 block/CU, 16 waves = 4/SIMD). Block = (batch, 64 Q rows).
// Waves 0-7 (producers): mm1 (K.Q^T MX) + exp + P-write  — R5's mm1 path verbatim.
// Waves 8-15 (consumers): mm2 (P.V MX) + vf loads + O    — R5's mm2 path verbatim.
// Same K-tile 128 / 32 iters / ONE barrier per iter / dbuf pairing as the validated 64.7us R5.
// Anti-phase overlap is STRUCTURAL: every SIMD hosts 2 producer + 2 consumer waves, so
// exp/VALU (producers) and MFMA/global-load (consumers) co-issue at every instant — no
// reliance on cross-block scheduling luck (R3/R6/R7 lesson).
// vf is single-buffered: loads issue right after the mm2 that consumed the old value
// (full iteration of flight), saving 16 VGPRs to keep union allocation <=128 (16-wave block).
__global__ __launch_bounds__(1024, 1) void tpe_main(
    const u8* __restrict__ xbf, const u8* __restrict__ xT,
    const float* __restrict__ sqv,
    const float* __restrict__ x, float* __restrict__ out) {
  __shared__ __align__(16) u8 Kt[2][32768];    // K tile 128 rows x 256 B (16-B-granule swizzled)
  __shared__ __align__(16) u8 Ps[2][64 * PSTR];
  __shared__ float lred[8][64];
  __shared__ float linv[64];

  const int tid = threadIdx.x;
  const int w = tid >> 6;       // 0..15
  const int lane = tid & 63;
  const int l15 = lane & 15, l31 = lane & 31;
  const int q4 = lane >> 4;     // 0..3
  const int q2 = lane >> 5;     // 0..1
  const bool prod = (w < 8);
  const int wp = w & 7;         // role-local wave id

  // XCD pinning: batch -> XCD pair (2 MB fp8 set stays L2-hot)
  const int blk = blockIdx.x;
  const int b = (blk & 7) >> 1;
  const int qt = ((blk >> 3) << 1) | (blk & 1);
  const int q0 = qt << 6;
  const long bL = (long)b * LL;

  const u8* kbat = xbf + (bL << 8);

  // ---- producer state: Q fragments (64 rows, 4 chains), qa ----
  i32x8 qmx[4][2];
  float qa[4];
  float rsacc[4] = {0.f, 0.f, 0.f, 0.f};
  // ---- consumer state: O accumulators, V fragments (single-buffered) ----
  f32x16 oacc[2];
  i32x8 vf[2];
  const u8* vseg = xT + (((long)(b << 8) + 32 * wp + l31) << 12);
  const int vk7 = l31 & 7;

  if (prod) {
    #pragma unroll
    for (int t = 0; t < 4; ++t) {
      const int row = q0 + 16 * t + l15;
      const u8* qrow = xbf + ((bL + row) << 8);
      #pragma unroll
      for (int u = 0; u < 2; ++u) {
        const int cb = 8 * u + 2 * q4;
        uint4 lo = *(const uint4*)(qrow + (((cb + 0) ^ l15) << 4));
        uint4 hi = *(const uint4*)(qrow + (((cb + 1) ^ l15) << 4));
        qmx[t][u] = PK16(lo, hi);
      }
      qa[t] = -0.5f * sqv[bL + row];
    }
  } else {
    #pragma unroll
    for (int rb = 0; rb < 2; ++rb)
      #pragma unroll
      for (int k = 0; k < 16; ++k) oacc[rb][k] = 0.f;
  }

  // prologue: DMA K tile 0 -> Kt[0] (32 KB, 2 rounds of 16 KB across 1024 threads)
  #pragma unroll
  for (int c = 0; c < 2; ++c) {
    int off = c * 16384 + tid * 16;
    dma16(kbat + off, Kt[0] + off);
  }
  __syncthreads();

#define TPE_ITER(IT, KCUR, KNXT, PPREV, PCUR)                                               \
  {                                                                                         \
    const int j0 = (IT) << 7;                                                               \
    if ((IT) < 31) { /* DMA K(it+1): full iteration of flight before the barrier drain */   \
      const u8* ks = kbat + ((long)((IT) + 1) << 15);                                       \
      _Pragma("unroll")                                                                     \
      for (int c = 0; c < 2; ++c) {                                                         \
        int off = c * 16384 + tid * 16;                                                     \
        dma16(ks + off, (KNXT) + off);                                                      \
      }                                                                                     \
    }                                                                                       \
    if (!prod) { /* ---- consumer: mm2 on tile IT-1, then vf loads for tile IT ---- */      \
      if ((IT) != 0) {                                                                      \
        __builtin_amdgcn_s_setprio(1);                                                      \
        _Pragma("unroll")                                                                   \
        for (int u = 0; u < 2; ++u) {                                                       \
          const u8* pr0 = (PPREV) + l31 * PSTR + 64 * u + 32 * q2;                          \
          i32x8 pa0 = PK16(*(const uint4*)(pr0), *(const uint4*)(pr0 + 16));                \
          i32x8 pa1 = PK16(*(const uint4*)(pr0 + 32 * PSTR),                                \
                           *(const uint4*)(pr0 + 32 * PSTR + 16));                          \
          oacc[0] = __builtin_amdgcn_mfma_scale_f32_32x32x64_f8f6f4(                        \
              pa0, vf[u], oacc[0], 0, 0, 0, ONE_SC, 0, ONE_SC);                             \
          oacc[1] = __builtin_amdgcn_mfma_scale_f32_32x32x64_f8f6f4(                        \
              pa1, vf[u], oacc[1], 0, 0, 0, ONE_SC, 0, ONE_SC);                             \
        }                                                                                   \
        __builtin_amdgcn_s_setprio(0);                                                      \
      }                                                                                     \
      _Pragma("unroll") /* vf for THIS tile (consumed next iter); overwrites consumed vf */ \
      for (int u = 0; u < 2; ++u) {                                                         \
        const int cb = 4 * u + 2 * q2;                                                      \
        uint4 v0 = *(const uint4*)(vseg + j0 + (((cb + 0) ^ vk7) << 4));                    \
        uint4 v1 = *(const uint4*)(vseg + j0 + (((cb + 1) ^ vk7) << 4));                    \
        vf[u] = PK16(v0, v1);                                                               \
      }                                                                                     \
    } else { /* ---- producer: mm1 MX on tile IT + exp -> P(IT) ---- */                     \
      float4 skv4 = *(const float4*)(sqv + bL + j0 + 16 * wp + 4 * q4);                     \
      const u8* kb2 = (KCUR) + (16 * wp + l15) * 256;                                       \
      f32x4 sacc[4];                                                                        \
      _Pragma("unroll")                                                                     \
      for (int t = 0; t < 4; ++t) {                                                         \
        sacc[t][0] = 0.f; sacc[t][1] = 0.f; sacc[t][2] = 0.f; sacc[t][3] = 0.f;             \
      }                                                                                     \
      __builtin_amdgcn_s_setprio(1);                                                        \
      _Pragma("unroll")                                                                     \
      for (int u = 0; u < 2; ++u) {                                                         \
        const int cb = 8 * u + 2 * q4;                                                      \
        uint4 klo = *(const uint4*)(kb2 + (((cb + 0) ^ l15) << 4));                         \
        uint4 khi = *(const uint4*)(kb2 + (((cb + 1) ^ l15) << 4));                         \
        i32x8 af = PK16(klo, khi);                                                          \
        _Pragma("unroll")                                                                   \
        for (int t = 0; t < 4; ++t)                                                         \
          sacc[t] = __builtin_amdgcn_mfma_scale_f32_16x16x128_f8f6f4(                       \
              af, qmx[t][u], sacc[t], 0, 0, 0, ONE_SC, 0, ONE_SC);                          \
      }                                                                                     \
      __builtin_amdgcn_s_setprio(0);                                                        \
      _Pragma("unroll") /* P = exp(min(0, g - 0.5||q||^2 - 0.5||k||^2)) -> LDS fp8 */       \
      for (int t = 0; t < 4; ++t) { /* lane: P[i=16t+l15][j=16wp+4q4+0..3] */               \
        float p0 = __expf(fminf(fmaf(sacc[t][0], GSCALE, qa[t] + skv4.x), 0.f));            \
        float p1 = __expf(fminf(fmaf(sacc[t][1], GSCALE, qa[t] + skv4.y), 0.f));            \
        float p2 = __expf(fminf(fmaf(sacc[t][2], GSCALE, qa[t] + skv4.z), 0.f));            \
        float p3 = __expf(fminf(fmaf(sacc[t][3], GSCALE, qa[t] + skv4.w), 0.f));            \
        rsacc[t] += (p0 + p1) + (p2 + p3);                                                  \
        int pk = __builtin_amdgcn_cvt_pk_fp8_f32(p0, p1, 0, false);                         \
        pk = __builtin_amdgcn_cvt_pk_fp8_f32(p2, p3, pk, true);                             \
        *(int*)((PCUR) + (16 * t + l15) * PSTR + 16 * wp + 4 * q4) = pk;                    \
      }                                                                                     \
    }                                                                                       \
    __syncthreads(); /* the ONLY barrier: P(it) visible, K(it+1) + vf(it) drained */        \
  }

  for (int it2 = 0; it2 < 16; ++it2) {
    TPE_ITER(2 * it2,     Kt[0], Kt[1], Ps[1], Ps[0])
    TPE_ITER(2 * it2 + 1, Kt[1], Kt[0], Ps[0], Ps[1])
  }
#undef TPE_ITER

  // ---- final mm2 (tile 31: P = Ps[1], V = vf) — consumers only ----
  if (!prod) {
    #pragma unroll
    for (int u = 0; u < 2; ++u) {
      const u8* pr0 = Ps[1] + l31 * PSTR + 64 * u + 32 * q2;
      i32x8 pa0 = PK16(*(const uint4*)(pr0), *(const uint4*)(pr0 + 16));
      i32x8 pa1 = PK16(*(const uint4*)(pr0 + 32 * PSTR), *(const uint4*)(pr0 + 32 * PSTR + 16));
      oacc[0] = __builtin_amdgcn_mfma_scale_f32_32x32x64_f8f6f4(
          pa0, vf[u], oacc[0], 0, 0, 0, ONE_SC, 0, ONE_SC);
      oacc[1] = __builtin_amdgcn_mfma_scale_f32_32x32x64_f8f6f4(
          pa1, vf[u], oacc[1], 0, 0, 0, ONE_SC, 0, ONE_SC);
    }
  }

  // ---- epilogue: rowsum reduce (producers); out = O/(16*l) + x + pe (consumers) ----
  if (prod) {
    #pragma unroll
    for (int t = 0; t < 4; ++t) {
      float r = rsacc[t];
      r += __shfl_xor(r, 16);
      r += __shfl_xor(r, 32);
      if (lane < 16) lred[wp][16 * t + l15] = r;
    }
  }
  __syncthreads();
  if (tid < 64) {
    float s = 0.f;
    #pragma unroll
    for (int ww = 0; ww < 8; ++ww) s += lred[ww][tid];
    linv[tid] = 0.0625f / s;   // 1/16 undoes V pre-scale
  }
  __syncthreads();
  if (!prod) {
    const int col = 32 * wp + l31;
    const float freq = __expf((float)(col & ~1) * FREQC);
    #pragma unroll
    for (int rb = 0; rb < 2; ++rb) {
      #pragma unroll
      for (int reg = 0; reg < 16; ++reg) {
        int row = 32 * rb + 4 * q2 + (reg & 3) + 8 * (reg >> 2);
        int l = q0 + row;
        float ang = (float)l * freq;
        float pv = (col & 1) ? __cosf(ang) : __sinf(ang);
        long off = ((bL + l) << 8) + col;
        out[off] = oacc[rb][reg] * linv[row] + x[off] + pv;
      }
    }
  }
}

extern "C" void kernel_launch(void* const* d_in, const int* in_sizes, int n_in,
                              void* d_out, int out_size, void* d_ws, size_t ws_size,
                              hipStream_t stream) {
  const float* x = (const float*)d_in[0];
  float* out = (float*)d_out;
  char* ws = (char*)d_ws;
  u8* xbf = (u8*)ws;                       // 4,194,304 B  (fp8 x, 16-B-granule swizzled rows)
  u8* xT = (u8*)(ws + 4194304);            // 4,194,304 B  (fp8 x^T, 16-B-granule swizzled segments)
  float* sq = (float*)(ws + 8388608);      //    65,536 B
  prep3<<<256, 512, 0, stream>>>(x, xbf, xT, sq);
  tpe_main<<<256, 1024, 0, stream>>>(xbf, xT, sq, x, out);
}

// Round 11
// 122.591 us; speedup vs baseline: 2.0217x; 2.0217x over previous
//
#include <hip/hip_runtime.h>

typedef unsigned char u8;
typedef float f32x4 __attribute__((ext_vector_type(4)));
typedef float f32x16 __attribute__((ext_vector_type(16)));
typedef int i32x8 __attribute__((ext_vector_type(8)));

#define LL 4096
#define PSTR 144              // P row stride (bytes): 16-B aligned 32-B spans; writes 2-way/free
#define SCALE 16.0f           // x pre-scale before fp8
#define GSCALE (1.0f/256.0f)  // undo SCALE^2 on the gram
#define FREQC (-0.03597789207803197f)   // -ln(10000)/256
#define ONE_SC 0x7F7F7F7F     // E8M0 scale bytes = 127 -> 2^0 = 1.0
#define VBSTR 1048576l        // xT per-batch stride: 32 windows x 32 KB (R10 bug: was 4194304)

__device__ __forceinline__ i32x8 PK16(uint4 a, uint4 b) {
  i32x8 r;
  r[0] = (int)a.x; r[1] = (int)a.y; r[2] = (int)a.z; r[3] = (int)a.w;
  r[4] = (int)b.x; r[5] = (int)b.y; r[6] = (int)b.z; r[7] = (int)b.w;
  return r;
}

typedef __attribute__((address_space(3))) u8 lds_u8;
typedef __attribute__((address_space(1))) u8 glb_u8;
__device__ __forceinline__ void dma16(const u8* g, u8* l) {
  __builtin_amdgcn_global_load_lds((const glb_u8*)g, (lds_u8*)l, 16, 0, 0);
}

// ---------------- prep4: fp8 convert + 16-B-granule swizzled layouts, TILED xT ----------------
//   xbf: row r (256 B): 16-B chunk c stored at ((c ^ (r&15))*16).   [unchanged, validated R5]
//   xT : [b][j-window 32][d 256][j 128]: each j-window of 128 rows is one CONTIGUOUS 32-KB
//        tile (tpe_main DMAs it linearly — kills R5's scattered vf loads: 32 L2 lines per
//        uint4, 12.5% line efficiency). Within a (window,d) row of 128 B: 16-B chunk c
//        (j = 16c..16c+15) at ((c ^ (d&7))*16). Per-batch stride VBSTR = 1 MB (4 MB total).
// GRID MUST BE 256 (4 b x 64 ch).
__global__ __launch_bounds__(512) void prep4(const float* __restrict__ x, u8* __restrict__ xbf,
                                             u8* __restrict__ xT, float* __restrict__ sq) {
  __shared__ u8 T2[256 * 80];       // col-major fp8: T2[d*80 + local_row], 16-B pad per column
  const int blk = blockIdx.x;
  const int b = blk >> 6, ch = blk & 63;
  const int j0 = ch << 6;           // first of this block's 64 rows
  const int tid = threadIdx.x;
  const int wv = tid >> 6, ln = tid & 63;
  const long bL = (long)b * LL;
  const float4* x4 = (const float4*)x + (bL + j0) * 64;
  unsigned* xb4 = (unsigned*)xbf + (bL + j0) * 64;

  #pragma unroll
  for (int g = 0; g < 2; ++g) {
    int pkw[4];
    #pragma unroll
    for (int ii = 0; ii < 4; ++ii) {
      const int row = 8 * wv + 4 * g + ii;                 // 0..63, wave owns 8 consecutive rows
      float4 v = x4[row * 64 + ln];                        // 1 KB contiguous per wave
      float s = v.x * v.x + v.y * v.y + v.z * v.z + v.w * v.w;
      #pragma unroll
      for (int o = 32; o; o >>= 1) s += __shfl_xor(s, o);
      if (ln == 0) sq[bL + j0 + row] = s;
      int pk = __builtin_amdgcn_cvt_pk_fp8_f32(v.x * SCALE, v.y * SCALE, 0, false);
      pk = __builtin_amdgcn_cvt_pk_fp8_f32(v.z * SCALE, v.w * SCALE, pk, true);
      // 16-B granule swizzle: dword ln belongs to chunk16 (ln>>2); position = chunk ^ (row&15)
      const int sdw = ((((ln >> 2) ^ ((j0 + row) & 15)) << 2)) | (ln & 3);
      xb4[row * 64 + sdw] = (unsigned)pk;                  // 256-B coalesced per wave
      pkw[ii] = pk;
    }
    // 4x4 byte transpose in registers (v_perm_b32), then dword writes into col-major T2.
    const int rb = 8 * wv + 4 * g;                         // first of 4 consecutive rows
    #pragma unroll
    for (int k = 0; k < 4; ++k) {
      const unsigned sel = (unsigned)(k | ((4 + k) << 8));
      unsigned m01 = __builtin_amdgcn_perm((unsigned)pkw[1], (unsigned)pkw[0], sel);
      unsigned m23 = __builtin_amdgcn_perm((unsigned)pkw[3], (unsigned)pkw[2], sel);
      unsigned tw  = __builtin_amdgcn_perm(m23, m01, 0x05040100u);
      *(unsigned*)(T2 + (4 * ln + k) * 80 + rb) = tw;      // rows rb..rb+3 at dim 4*ln+k
    }
  }
  __syncthreads();
  // Phase 2: per d-row, emit this block's 4 16-B chunks into the tiled xT (64-B bursts).
  #pragma unroll
  for (int db = 0; db < 2; ++db) {
    const int d = db * 128 + (tid >> 2);
    const int cl = tid & 3;                                // local chunk16 (16 local rows)
    const int c16 = ((ch & 1) << 2) | cl;                  // global chunk16 within window
    const int p = c16 ^ (d & 7);                           // swizzled position
    uint4 ov = *(const uint4*)(T2 + d * 80 + 16 * cl);     // 16 consecutive local rows at dim d
    // [b][window=ch>>1][d][p]: window tile contiguous 32 KB; batch stride 1 MB
    *(uint4*)(xT + (long)b * VBSTR + (ch >> 1) * 32768 + d * 128 + (p << 4)) = ov;
  }
}

// ---------------- main kernel: R5 structure + LDS-staged V (coalesced DMA) ----------------
// 256 blocks x 512 thr (1 block/CU, 8 waves). Block = (batch, 64 Q rows).
// K-tile 128, 32 iters, ONE barrier/iter. Identical pipeline to the validated 64.7us R5;
// ONLY change: vf fragments come from a double-buffered Vt LDS tile (32 KB/iter, DMA'd
// linearly from the tiled xT alongside Kt) instead of per-lane scattered global loads.
//   mm1: 4x ds_read_b128 + 8x mfma_scale_16x16x128 (4 chains x 2).
//   mm2: 8x ds_read_b128 + 4x mfma_scale_32x32x64.
//   vf : 4x ds_read_b128 from Vt[cur] (held in regs across the barrier, consumed next iter).
// LDS: Kt 64K + Vt 64K + Ps 18K + red 2.3K = 151.8 KB (< 160 KB, 1 block/CU).
__global__ __launch_bounds__(512, 2) void tpe_main(
    const u8* __restrict__ xbf, const u8* __restrict__ xT,
    const float* __restrict__ sqv,
    const float* __restrict__ x, float* __restrict__ out) {
  __shared__ __align__(16) u8 Kt[2][32768];    // K tile 128 rows x 256 B (16-B-granule swizzled)
  __shared__ __align__(16) u8 Vt[2][32768];    // V tile [d 256][j 128 swizzled] (tiled xT window)
  __shared__ __align__(16) u8 Ps[2][64 * PSTR];
  __shared__ float lred[8][64];
  __shared__ float linv[64];

  const int tid = threadIdx.x;
  const int w = tid >> 6;
  const int lane = tid & 63;
  const int l15 = lane & 15, l31 = lane & 31;
  const int q4 = lane >> 4;   // 0..3
  const int q2 = lane >> 5;   // 0..1

  // XCD pinning: batch -> XCD pair (2 MB fp8 set stays L2-hot)
  const int blk = blockIdx.x;
  const int b = (blk & 7) >> 1;
  const int qt = ((blk >> 3) << 1) | (blk & 1);
  const int q0 = qt << 6;
  const long bL = (long)b * LL;

  // Q fragments (all 64 rows, 4 chains), MX grouping: qmx[t][u] = K bytes [128u+32q4, +32)
  i32x8 qmx[4][2];
  float qa[4];
  #pragma unroll
  for (int t = 0; t < 4; ++t) {
    const int row = q0 + 16 * t + l15;
    const u8* qrow = xbf + ((bL + row) << 8);
    #pragma unroll
    for (int u = 0; u < 2; ++u) {
      const int cb = 8 * u + 2 * q4;
      uint4 lo = *(const uint4*)(qrow + (((cb + 0) ^ l15) << 4));
      uint4 hi = *(const uint4*)(qrow + (((cb + 1) ^ l15) << 4));
      qmx[t][u] = PK16(lo, hi);
    }
    qa[t] = -0.5f * sqv[bL + row];
  }

  f32x16 oacc[2];
  #pragma unroll
  for (int rb = 0; rb < 2; ++rb)
    #pragma unroll
    for (int k = 0; k < 16; ++k) oacc[rb][k] = 0.f;
  float rsacc[4] = {0.f, 0.f, 0.f, 0.f};

  const u8* kbat = xbf + (bL << 8);
  const u8* vbat = xT + (long)b * VBSTR;
  // V fragment row inside Vt: d = 32w + l31 (this wave's O columns); chunk key = d&7 = l31&7
  const int vrow = (32 * w + l31) << 7;
  const int vk7 = l31 & 7;

  i32x8 vfA[2], vfB[2];

  // prologue: DMA K tile 0 + V tile 0
  #pragma unroll
  for (int c = 0; c < 4; ++c) {
    int off = c * 8192 + tid * 16;
    dma16(kbat + off, Kt[0] + off);
    dma16(vbat + off, Vt[0] + off);
  }
  __syncthreads();

#define TPE_ITER(IT, KCUR, KNXT, VCUR, VNXT, PPREV, PCUR, VFC, VFN)                         \
  {                                                                                         \
    const int j0 = (IT) << 7;                                                               \
    if ((IT) < 31) { /* DMA K,V(it+1): full iteration of flight before the barrier drain */ \
      const u8* ks = kbat + ((long)((IT) + 1) << 15);                                       \
      const u8* vs = vbat + ((long)((IT) + 1) << 15);                                       \
      _Pragma("unroll")                                                                     \
      for (int c = 0; c < 4; ++c) {                                                         \
        int off = c * 8192 + tid * 16;                                                      \
        dma16(ks + off, (KNXT) + off);                                                      \
        dma16(vs + off, (VNXT) + off);                                                      \
      }                                                                                     \
    }                                                                                       \
    float4 skv4 = *(const float4*)(sqv + bL + j0 + 16 * w + 4 * q4);                        \
    if ((IT) != 0) { /* mm2 MX on previous tile: A = P(it-1) rows (2x b128), B = vf regs */ \
      _Pragma("unroll")                                                                     \
      for (int u = 0; u < 2; ++u) {                                                         \
        const u8* pr0 = (PPREV) + l31 * PSTR + 64 * u + 32 * q2;                            \
        i32x8 pa0 = PK16(*(const uint4*)(pr0), *(const uint4*)(pr0 + 16));                  \
        i32x8 pa1 = PK16(*(const uint4*)(pr0 + 32 * PSTR),                                  \
                         *(const uint4*)(pr0 + 32 * PSTR + 16));                            \
        oacc[0] = __builtin_amdgcn_mfma_scale_f32_32x32x64_f8f6f4(                          \
            pa0, VFC[u], oacc[0], 0, 0, 0, ONE_SC, 0, ONE_SC);                              \
        oacc[1] = __builtin_amdgcn_mfma_scale_f32_32x32x64_f8f6f4(                          \
            pa1, VFC[u], oacc[1], 0, 0, 0, ONE_SC, 0, ONE_SC);                              \
      }                                                                                     \
    }                                                                                       \
    _Pragma("unroll") /* vf for THIS tile from Vt[cur] LDS (consumed next iter) */          \
    for (int u = 0; u < 2; ++u) {                                                           \
      const int cb = 4 * u + 2 * q2;                                                        \
      uint4 v0 = *(const uint4*)((VCUR) + vrow + (((cb + 0) ^ vk7) << 4));                  \
      uint4 v1 = *(const uint4*)((VCUR) + vrow + (((cb + 1) ^ vk7) << 4));                  \
      VFN[u] = PK16(v0, v1);                                                                \
    }                                                                                       \
    { /* mm1 MX: S^T = K.Q^T, 8-MFMA run, 4 independent chains */                           \
      const int krow = 16 * w + l15;                                                        \
      const u8* kb2 = (KCUR) + krow * 256;                                                  \
      f32x4 sacc[4];                                                                        \
      _Pragma("unroll")                                                                     \
      for (int t = 0; t < 4; ++t) {                                                         \
        sacc[t][0] = 0.f; sacc[t][1] = 0.f; sacc[t][2] = 0.f; sacc[t][3] = 0.f;             \
      }                                                                                     \
      _Pragma("unroll")                                                                     \
      for (int u = 0; u < 2; ++u) {                                                         \
        const int cb = 8 * u + 2 * q4;                                                      \
        uint4 klo = *(const uint4*)(kb2 + (((cb + 0) ^ l15) << 4));                         \
        uint4 khi = *(const uint4*)(kb2 + (((cb + 1) ^ l15) << 4));                         \
        i32x8 af = PK16(klo, khi);                                                          \
        _Pragma("unroll")                                                                   \
        for (int t = 0; t < 4; ++t)                                                         \
          sacc[t] = __builtin_amdgcn_mfma_scale_f32_16x16x128_f8f6f4(                       \
              af, qmx[t][u], sacc[t], 0, 0, 0, ONE_SC, 0, ONE_SC);                          \
      }                                                                                     \
      _Pragma("unroll") /* P = exp(min(0, g - 0.5||q||^2 - 0.5||k||^2)) -> LDS fp8 */       \
      for (int t = 0; t < 4; ++t) { /* lane: P[i=16t+l15][j=16w+4q4+0..3] */                \
        float p0 = __expf(fminf(fmaf(sacc[t][0], GSCALE, qa[t] + skv4.x), 0.f));            \
        float p1 = __expf(fminf(fmaf(sacc[t][1], GSCALE, qa[t] + skv4.y), 0.f));            \
        float p2 = __expf(fminf(fmaf(sacc[t][2], GSCALE, qa[t] + skv4.z), 0.f));            \
        float p3 = __expf(fminf(fmaf(sacc[t][3], GSCALE, qa[t] + skv4.w), 0.f));            \
        rsacc[t] += (p0 + p1) + (p2 + p3);                                                  \
        int pk = __builtin_amdgcn_cvt_pk_fp8_f32(p0, p1, 0, false);                         \
        pk = __builtin_amdgcn_cvt_pk_fp8_f32(p2, p3, pk, true);                             \
        *(int*)((PCUR) + (16 * t + l15) * PSTR + 16 * w + 4 * q4) = pk;                     \
      }                                                                                     \
    }                                                                                       \
    __syncthreads(); /* the ONLY barrier: P(it) visible, K/V(it+1) drained */               \
  }

  for (int it2 = 0; it2 < 16; ++it2) {
    TPE_ITER(2 * it2,     Kt[0], Kt[1], Vt[0], Vt[1], Ps[1], Ps[0], vfA, vfB)
    TPE_ITER(2 * it2 + 1, Kt[1], Kt[0], Vt[1], Vt[0], Ps[0], Ps[1], vfB, vfA)
  }
#undef TPE_ITER

  // ---- final mm2 (tile 31: P = Ps[1], V = vfA), MX form ----
  #pragma unroll
  for (int u = 0; u < 2; ++u) {
    const u8* pr0 = Ps[1] + l31 * PSTR + 64 * u + 32 * q2;
    i32x8 pa0 = PK16(*(const uint4*)(pr0), *(const uint4*)(pr0 + 16));
    i32x8 pa1 = PK16(*(const uint4*)(pr0 + 32 * PSTR), *(const uint4*)(pr0 + 32 * PSTR + 16));
    oacc[0] = __builtin_amdgcn_mfma_scale_f32_32x32x64_f8f6f4(
        pa0, vfA[u], oacc[0], 0, 0, 0, ONE_SC, 0, ONE_SC);
    oacc[1] = __builtin_amdgcn_mfma_scale_f32_32x32x64_f8f6f4(
        pa1, vfA[u], oacc[1], 0, 0, 0, ONE_SC, 0, ONE_SC);
  }

  // ---- epilogue: rowsum reduce; out = O/(16*l) + x + pe(inline) ----
  #pragma unroll
  for (int t = 0; t < 4; ++t) {
    float r = rsacc[t];
    r += __shfl_xor(r, 16);
    r += __shfl_xor(r, 32);
    if (lane < 16) lred[w][16 * t + l15] = r;
  }
  __syncthreads();
  if (tid < 64) {
    float s = 0.f;
    #pragma unroll
    for (int ww = 0; ww < 8; ++ww) s += lred[ww][tid];
    linv[tid] = 0.0625f / s;   // 1/16 undoes V pre-scale
  }
  __syncthreads();
  const int col = 32 * w + l31;
  const float freq = __expf((float)(col & ~1) * FREQC);
  #pragma unroll
  for (int rb = 0; rb < 2; ++rb) {
    #pragma unroll
    for (int reg = 0; reg < 16; ++reg) {
      int row = 32 * rb + 4 * q2 + (reg & 3) + 8 * (reg >> 2);
      int l = q0 + row;
      float ang = (float)l * freq;
      float pv = (col & 1) ? __cosf(ang) : __sinf(ang);
      long off = ((bL + l) << 8) + col;
      out[off] = oacc[rb][reg] * linv[row] + x[off] + pv;
    }
  }
}

extern "C" void kernel_launch(void* const* d_in, const int* in_sizes, int n_in,
                              void* d_out, int out_size, void* d_ws, size_t ws_size,
                              hipStream_t stream) {
  const float* x = (const float*)d_in[0];
  float* out = (float*)d_out;
  char* ws = (char*)d_ws;
  u8* xbf = (u8*)ws;                       // 4,194,304 B  (fp8 x, 16-B-granule swizzled rows)
  u8* xT = (u8*)(ws + 4194304);            // 4,194,304 B  (fp8 x^T, tiled [b][jw][d][j-swz], 1 MB/batch)
  float* sq = (float*)(ws + 8388608);      //    65,536 B
  prep4<<<256, 512, 0, stream>>>(x, xbf, xT, sq);
  tpe_main<<<256, 512, 0, stream>>>(xbf, xT, sq, x, out);
}